// Round 5
// baseline (1241.876 us; speedup 1.0000x reference)
//
#include <hip/hip_runtime.h>

#define NN 25600
#define EE 409600
#define BB 64
#define NGR 400
#define DD 128
#define HH 64
#define RR 32
#define EA 204800              // available (odd) edges
#define TPL (EA/32)            // tiles per label bucket = 6400

// workspace layout (float offsets)
#define OFF_AGGE   0
#define OFF_AGGO   1638400
#define OFF_NMASK  3276800
#define OFF_POOLF  3302400
#define OFF_POOLS  3304448
#define OFF_CNT    3306496
#define OFF_LCOUNT 3306560     // 4 uints
#define OFF_SEGKEY 3306568     // 64 u64 (8B-aligned)
#define OFF_CNT2   3306696     // 128 uints (graph x parity counters)
#define ZERO_END   3306824
#define OFF_H      3306824
#define OFF_NRA    4945224     // also overlays ELIST2 (consumed by k_edges before k_node writes)
#define OFF_BIAS1  5764424
#define OFF_ELIST  5772616     // 4*EA ints
// ELIST2: 128 buckets x 4096 ints at OFF_NRA (524288 <= 819200)
// weight packs overlay AGGE (dead after k_node); written by k_pack after k_node

typedef short bf16x8 __attribute__((ext_vector_type(8)));
typedef float floatx4 __attribute__((ext_vector_type(4)));
#define MFMA16 __builtin_amdgcn_mfma_f32_16x16x32_bf16

__device__ __forceinline__ float eluf(float v){ return v > 0.f ? v : expm1f(v); }

__device__ __forceinline__ void splitbf(float v, unsigned short& h, unsigned short& l){
  const unsigned u = __float_as_uint(v);
  h = (unsigned short)(u >> 16);
  const float hf = __uint_as_float(u & 0xFFFF0000u);
  l = (unsigned short)(__float_as_uint(v - hf) >> 16);
}
__device__ __forceinline__ float bf2f(unsigned short s){
  return __uint_as_float(((unsigned)s) << 16);
}

__device__ __forceinline__ unsigned long long packkey(float f, unsigned idx){
  unsigned u = __float_as_uint(f);
  u = (u & 0x80000000u) ? ~u : (u | 0x80000000u);
  return ((unsigned long long)u << 32) | (unsigned long long)(0xFFFFFFFFu - idx);
}

// ---------------- h = elu(x @ Wm1) ----------------
__global__ __launch_bounds__(256) void k_h(const float* __restrict__ x,
                                           const float* __restrict__ Wm1,
                                           float* __restrict__ h)
{
  __shared__ float xs[64][129];
  const int tid = threadIdx.x;
  const int n0 = blockIdx.x * 64;
  for (int idx = tid; idx < 64*128; idx += 256){
    int r = idx >> 7, c = idx & 127;
    xs[r][c] = x[(n0 + r)*DD + c];
  }
  __syncthreads();
  const int m = tid & 63, ng = tid >> 6;
  float4 acc[4];
  #pragma unroll
  for (int c = 0; c < 4; ++c) acc[c] = make_float4(0.f,0.f,0.f,0.f);
  for (int k = 0; k < 128; ++k){
    const float a = xs[m][k];
    const float* wr = Wm1 + k*64 + ng*16;
    #pragma unroll
    for (int c = 0; c < 4; ++c){
      const float4 w = *(const float4*)(wr + 4*c);
      acc[c].x += a*w.x; acc[c].y += a*w.y; acc[c].z += a*w.z; acc[c].w += a*w.w;
    }
  }
  float* hp = h + (n0 + m)*HH + ng*16;
  #pragma unroll
  for (int c = 0; c < 4; ++c){
    hp[4*c+0] = eluf(acc[c].x); hp[4*c+1] = eluf(acc[c].y);
    hp[4*c+2] = eluf(acc[c].z); hp[4*c+3] = eluf(acc[c].w);
  }
}

// ---------------- bucket ALL edges by (graph, parity) + odd edges by label ----------------
__global__ __launch_bounds__(256) void k_bucket(const int* __restrict__ ei,
                                                const int* __restrict__ y,
                                                unsigned* __restrict__ lcount,
                                                int* __restrict__ elist,
                                                unsigned* __restrict__ cnt2,
                                                int* __restrict__ elist2)
{
  const int e = blockIdx.x*256 + threadIdx.x;   // EE threads exactly
  const int d = ei[EE + e];
  const int g = d / NGR;
  const int p = e & 1;
  const int bkt = g*2 + p;
  const unsigned pos = atomicAdd(&cnt2[bkt], 1u);
  elist2[bkt*4096 + (int)pos] = e;
  if (p){   // label bucket for available (odd) edges
    const int l = y[g];
    const int lane = threadIdx.x & 63;
    const int i = e >> 1;
    #pragma unroll
    for (int lb = 0; lb < 4; ++lb){
      const unsigned long long msk = __ballot(l == lb);
      if (l == lb){
        const int leader = __builtin_ctzll(msk);
        const unsigned cnt = (unsigned)__popcll(msk);
        unsigned base = 0;
        if (lane == leader) base = atomicAdd(&lcount[lb], cnt);
        base = (unsigned)__shfl((int)base, leader);
        const unsigned rank = (unsigned)__popcll(msk & ((1ull << lane) - 1ull));
        elist[lb*EA + (int)(base + rank)] = i;
      }
    }
  }
}

// ---------------- edge aggregation: drain pre-bucketed edges into LDS ----------------
// block = g*4 + p*2 + ch; LDS 400x36 accumulator (stride 36 dwords => bank spread by d)
__global__ __launch_bounds__(256) void k_edges(const int* __restrict__ ei,
                                               const float* __restrict__ h,
                                               const unsigned* __restrict__ cnt2,
                                               const int* __restrict__ elist2,
                                               float* __restrict__ aggE,
                                               float* __restrict__ aggO,
                                               float* __restrict__ nmask)
{
  __shared__ float acc[400*36];
  __shared__ unsigned char mk[400];
  const int b = blockIdx.x;
  const int g = b >> 2, p = (b >> 1) & 1, ch = b & 1;
  const int tid = threadIdx.x;
  const int nlo = g * NGR;
  for (int i = tid; i < 400*36; i += 256) acc[i] = 0.f;
  if (tid < 400) mk[tid] = 0;
  __syncthreads();
  const int bkt = g*2 + p;
  const int n = (int)cnt2[bkt];
  const int j0 = tid >> 3, c8 = tid & 7;
  const bool domask = (p == 0) && (ch == 0) && (c8 == 0);
  for (int j = j0; j < n; j += 32){
    const int e = elist2[bkt*4096 + j];
    const int s = ei[e];
    const int d = ei[EE + e] - nlo;
    const float4 v = *(const float4*)(h + s*HH + ch*32 + c8*4);
    float* ap = &acc[d*36 + c8*4];
    atomicAdd(ap+0, v.x); atomicAdd(ap+1, v.y);
    atomicAdd(ap+2, v.z); atomicAdd(ap+3, v.w);
    if (domask){ mk[s - nlo] = 1; mk[d] = 1; }
  }
  __syncthreads();
  float* agg = p ? aggO : aggE;
  for (int idx = tid; idx < 400*32; idx += 256){
    const int d = idx >> 5, col = idx & 31;
    agg[(nlo + d)*HH + ch*32 + col] = acc[d*36 + col];
  }
  if (p == 0 && ch == 0){
    for (int idx = tid; idx < 400; idx += 256) nmask[nlo + idx] = (float)mk[idx];
  }
}

// ---------------- node reps + pooled sums (LDS-reduced pools) ----------------
__global__ __launch_bounds__(256) void k_node(const float* __restrict__ h,
                                              const float* __restrict__ aggE,
                                              const float* __restrict__ aggO,
                                              const float* __restrict__ Wm2,
                                              const float* __restrict__ nmask,
                                              float* __restrict__ nra,
                                              float* __restrict__ poolF,
                                              float* __restrict__ poolS,
                                              float* __restrict__ cntArr)
{
  __shared__ float hs[8][64], ae[8][64], ao[8][64];
  __shared__ float wm[64][32];
  __shared__ float rf[8][32], rs[8][32], rc[8];
  const int tid = threadIdx.x;
  const int n0 = blockIdx.x * 8;
  for (int idx = tid; idx < 512; idx += 256){
    int i = idx >> 6, k = idx & 63, n = n0 + i;
    hs[i][k] = h[n*HH + k];
    ae[i][k] = aggE[n*HH + k];
    ao[i][k] = aggO[n*HH + k];
  }
  for (int idx = tid; idx < 2048; idx += 256) wm[idx >> 5][idx & 31] = Wm2[idx];
  __syncthreads();
  const int i = tid >> 5, r = tid & 31;
  const int n = n0 + i;
  float aF = 0.f, aS = 0.f, aA = 0.f;
  #pragma unroll 4
  for (int k = 0; k < 64; ++k){
    const float th = hs[i][k], te = ae[i][k], to = ao[i][k], w = wm[k][r];
    aF += (th + te + to) * w;
    aS += (th + te) * w;
    aA += (th + to) * w;
  }
  aF = eluf(aF); aS = eluf(aS); aA = eluf(aA);
  nra[n*RR + r] = aA;
  const float msk = nmask[n];
  rf[i][r] = aF;
  rs[i][r] = (msk != 0.f) ? aS : 0.f;
  if (r == 0) rc[i] = (msk != 0.f) ? 1.f : 0.f;
  __syncthreads();
  const int g = n0 / NGR;
  if (tid < 32){
    float sf = 0.f, ss = 0.f;
    #pragma unroll
    for (int k = 0; k < 8; ++k){ sf += rf[k][tid]; ss += rs[k][tid]; }
    atomicAdd(&poolF[g*RR + tid], sf);
    atomicAdd(&poolS[g*RR + tid], ss);
  } else if (tid == 32){
    float sc = 0.f;
    #pragma unroll
    for (int k = 0; k < 8; ++k) sc += rc[k];
    atomicAdd(&cntArr[g], sc);
  }
}

// ---------------- pack all MLP weights into MFMA B-fragment hi/lo bf16 ----------------
__global__ __launch_bounds__(256) void k_pack(const float* __restrict__ W1,
                                              const float* __restrict__ W2,
                                              const float* __restrict__ W3,
                                              const float* __restrict__ We1,
                                              const float* __restrict__ We2,
                                              unsigned short* __restrict__ pk)
{
  const int t = blockIdx.x*4 + (threadIdx.x >> 6);   // 0..239
  const int L = threadIdx.x & 63;
  int tl, KT, N; const float* W;
  if (t < 32)      { tl = t;      KT = 2; N = 256; W = W1; }
  else if (t < 96) { tl = t-32;   KT = 8; N = 128; W = W2; }
  else if (t < 112){ tl = t-96;   KT = 4; N = 64;  W = W3; }
  else if (t < 176){ int u = t-112; int lb = u >> 4; tl = u & 15; KT = 2; N = 128; W = We1 + lb*16384; }
  else             { int u = t-176; int lb = u >> 4; tl = u & 15; KT = 4; N = 64;  W = We2 + lb*8192; }
  const int nt = tl / KT, kt = tl % KT;
  const int krow = kt*32 + (L >> 4)*8;
  const int col  = nt*16 + (L & 15);
  unsigned short* dh = pk + (unsigned)t*1024 + L*8;
  unsigned short* dl = dh + 512;
  #pragma unroll
  for (int j = 0; j < 8; ++j){
    const float v = W[(krow + j)*N + col];
    unsigned short h, l2;
    splitbf(v, h, l2);
    dh[j] = h; dl[j] = l2;
  }
}

// ---------------- per-graph diff and explainer bias ----------------
__global__ __launch_bounds__(128) void k_graph(const float* __restrict__ poolF,
                                               const float* __restrict__ poolS,
                                               const float* __restrict__ cnt,
                                               const float* __restrict__ Wg,
                                               const int* __restrict__ y,
                                               const float* __restrict__ We1,
                                               const float* __restrict__ be1,
                                               float* __restrict__ bias1)
{
  __shared__ float pd[32];
  __shared__ float dg[64];
  const int g = blockIdx.x, tid = threadIdx.x;
  if (tid < 32){
    const float c = cnt[g];
    const float pf = poolF[g*RR + tid] * (1.0f/400.0f);
    const float ps = poolS[g*RR + tid] / fmaxf(c, 1.0f);
    pd[tid] = pf - ps;
  }
  __syncthreads();
  if (tid < 64){
    float a = 0.f;
    #pragma unroll
    for (int r = 0; r < 32; ++r) a += pd[r] * Wg[r*64 + tid];
    dg[tid] = a;
  }
  __syncthreads();
  const int l = y[g];
  float acc = be1[l*128 + tid];
  #pragma unroll 8
  for (int j = 0; j < 64; ++j) acc += dg[j] * We1[l*16384 + (64 + j)*128 + tid];
  bias1[g*128 + tid] = acc;
}

// ---------------- MFMA split-bf16 layer: 4 waves split N, double-buffered B prefetch ----------------
template<int K, int N, bool DOELU, int SIN, int SOUT, bool ROWBIAS>
__device__ __forceinline__ void layerM(const unsigned short (*__restrict__ Ih)[SIN],
                                       const unsigned short (*__restrict__ Il)[SIN],
                                       unsigned short (*__restrict__ Oh)[SOUT],
                                       unsigned short (*__restrict__ Ol)[SOUT],
                                       const unsigned short* __restrict__ pk,
                                       const float* __restrict__ bias,
                                       const int* __restrict__ gA,
                                       int wv, int lane)
{
  constexpr int KT = K/32, NTW = N/64;   // k-tiles; n-tiles per wave
  const int c = lane & 15, q = lane >> 4;
  floatx4 acc[2][NTW];
  #pragma unroll
  for (int ms = 0; ms < 2; ++ms){
    #pragma unroll
    for (int nt = 0; nt < NTW; ++nt){
      const int col = (wv*NTW + nt)*16 + c;
      if (ROWBIAS){
        #pragma unroll
        for (int r = 0; r < 4; ++r)
          acc[ms][nt][r] = bias[gA[ms*16 + q*4 + r]*128 + col];
      } else {
        const float bv = bias[col];
        acc[ms][nt][0]=bv; acc[ms][nt][1]=bv; acc[ms][nt][2]=bv; acc[ms][nt][3]=bv;
      }
    }
  }
  bf16x8 BH[2][NTW], BL[2][NTW];
  #pragma unroll
  for (int nt = 0; nt < NTW; ++nt){
    const unsigned short* bp = pk + (unsigned)((wv*NTW + nt)*KT*1024) + lane*8;
    BH[0][nt] = *(const bf16x8*)bp;
    BL[0][nt] = *(const bf16x8*)(bp + 512);
  }
  #pragma unroll
  for (int kt = 0; kt < KT; ++kt){
    const int cur = kt & 1, nxt = cur ^ 1;
    if (kt + 1 < KT){
      #pragma unroll
      for (int nt = 0; nt < NTW; ++nt){
        const unsigned short* bp = pk + (unsigned)(((wv*NTW + nt)*KT + kt + 1)*1024) + lane*8;
        BH[nxt][nt] = *(const bf16x8*)bp;
        BL[nxt][nt] = *(const bf16x8*)(bp + 512);
      }
    }
    const bf16x8 ah0 = *(const bf16x8*)&Ih[c     ][kt*32 + q*8];
    const bf16x8 al0 = *(const bf16x8*)&Il[c     ][kt*32 + q*8];
    const bf16x8 ah1 = *(const bf16x8*)&Ih[16 + c][kt*32 + q*8];
    const bf16x8 al1 = *(const bf16x8*)&Il[16 + c][kt*32 + q*8];
    #pragma unroll
    for (int nt = 0; nt < NTW; ++nt){
      acc[0][nt] = MFMA16(ah0, BH[cur][nt], acc[0][nt], 0, 0, 0);
      acc[1][nt] = MFMA16(ah1, BH[cur][nt], acc[1][nt], 0, 0, 0);
      acc[0][nt] = MFMA16(al0, BH[cur][nt], acc[0][nt], 0, 0, 0);
      acc[1][nt] = MFMA16(al1, BH[cur][nt], acc[1][nt], 0, 0, 0);
      acc[0][nt] = MFMA16(ah0, BL[cur][nt], acc[0][nt], 0, 0, 0);
      acc[1][nt] = MFMA16(ah1, BL[cur][nt], acc[1][nt], 0, 0, 0);
    }
  }
  #pragma unroll
  for (int ms = 0; ms < 2; ++ms){
    #pragma unroll
    for (int nt = 0; nt < NTW; ++nt){
      const int col = (wv*NTW + nt)*16 + c;
      #pragma unroll
      for (int r = 0; r < 4; ++r){
        float v = acc[ms][nt][r];
        if (DOELU) v = eluf(v);
        unsigned short h, l2;
        splitbf(v, h, l2);
        const int row = ms*16 + q*4 + r;
        Oh[row][col] = h; Ol[row][col] = l2;
      }
    }
  }
}

// ---------------- fused per-edge MLP (MFMA) ----------------
__global__ __launch_bounds__(256, 3) void k_mlp(const float* __restrict__ nra,
                                             const int* __restrict__ ei,
                                             const unsigned short* __restrict__ pk,
                                             const float* __restrict__ b1,
                                             const float* __restrict__ b2,
                                             const float* __restrict__ b3,
                                             const float* __restrict__ be2,
                                             const float* __restrict__ We3,
                                             const float* __restrict__ be3,
                                             const float* __restrict__ bias1,
                                             const int* __restrict__ elist,
                                             const unsigned* __restrict__ lcount,
                                             float* __restrict__ probs,
                                             unsigned long long* __restrict__ segkey)
{
  __shared__ unsigned short Xh[32][264], Xl[32][264];
  __shared__ unsigned short Yh[32][136], Yl[32][136];
  __shared__ int iA[32], sA[32], dA[32], gA[32];
  const int l = blockIdx.x / TPL;
  const int t = blockIdx.x % TPL;
  const unsigned cnt = lcount[l];
  const int base = t * 32;
  if ((unsigned)base >= cnt) return;
  const int valid = min(32, (int)(cnt - (unsigned)base));
  const int tid = threadIdx.x;
  const int wv = tid >> 6, lane = tid & 63;
  if (tid < 32){
    const int mm = (tid < valid) ? tid : 0;
    const int i = elist[l*EA + base + mm];
    const int e = 2*i + 1;
    const int s = ei[e], d = ei[EE + e];
    iA[tid] = i; sA[tid] = s; dA[tid] = d; gA[tid] = s / NGR;
  }
  __syncthreads();
  { // gather in0 = [nr_ava[src] | nr_ava[dst]] split into Yh/Yl cols 0..63
    const int m = tid >> 3, t8 = tid & 7;
    const int node = (t8 < 4) ? sA[m] : dA[m];
    const int off = (t8 & 3) * 8;
    const float* np_ = nra + node*RR + off;
    const int cb = ((t8 < 4) ? 0 : 32) + off;
    #pragma unroll
    for (int jj = 0; jj < 8; ++jj){
      unsigned short h, l2;
      splitbf(np_[jj], h, l2);
      Yh[m][cb + jj] = h; Yl[m][cb + jj] = l2;
    }
  }
  __syncthreads();
  layerM< 64,256,true ,136,264,false>(Yh,Yl,Xh,Xl, pk,                     b1,         gA, wv, lane);
  __syncthreads();
  layerM<256,128,true ,264,136,false>(Xh,Xl,Yh,Yl, pk + 32*1024,           b2,         gA, wv, lane);
  __syncthreads();
  layerM<128, 64,false,136,264,false>(Yh,Yl,Xh,Xl, pk + 96*1024,           b3,         gA, wv, lane);
  __syncthreads();
  layerM< 64,128,true ,264,136,true >(Xh,Xl,Yh,Yl, pk + (112 + l*16)*1024, bias1,      gA, wv, lane);
  __syncthreads();
  layerM<128, 64,true ,136,264,false>(Yh,Yl,Xh,Xl, pk + (176 + l*16)*1024, be2 + l*64, gA, wv, lane);
  __syncthreads();
  if (tid < 128){ // score = X5 . We3[l] + be3[l]; 4 threads per edge
    const int m = tid >> 2, part = tid & 3;
    const float* w3p = We3 + l*64 + part*16;
    const unsigned short* xh = &Xh[m][part*16];
    const unsigned short* xl = &Xl[m][part*16];
    float s = 0.f;
    #pragma unroll
    for (int kk = 0; kk < 16; ++kk)
      s += (bf2f(xh[kk]) + bf2f(xl[kk])) * w3p[kk];
    s += __shfl_down(s, 2);
    s += __shfl_down(s, 1);
    if (part == 0 && m < valid){
      s += be3[l];
      const int i = iA[m];
      probs[i] = s;
      atomicMax(&segkey[gA[m]], packkey(s, (unsigned)i));
    }
  }
}

// ---------------- finalize outputs ----------------
__global__ void k_final(const unsigned long long* __restrict__ segkey, float* __restrict__ out)
{
  const int g = threadIdx.x;
  if (g < BB){
    const unsigned long long key = segkey[g];
    const unsigned u = (unsigned)(key >> 32);
    const float mx = (u & 0x80000000u) ? __uint_as_float(u & 0x7FFFFFFFu)
                                       : __uint_as_float(~u);
    const unsigned idx = 0xFFFFFFFFu - (unsigned)(key & 0xFFFFFFFFull);
    out[EA + g]        = mx;
    out[EA + BB + g]   = (float)idx;
    out[EA + 2*BB + g] = (float)g;
  }
}

extern "C" void kernel_launch(void* const* d_in, const int* in_sizes, int n_in,
                              void* d_out, int out_size, void* d_ws, size_t ws_size,
                              hipStream_t stream)
{
  (void)in_sizes; (void)n_in; (void)out_size; (void)ws_size;
  const float* x   = (const float*)d_in[0];
  const int*   ei  = (const int*)  d_in[1];
  const int*   y   = (const int*)  d_in[3];
  const float* Wm1 = (const float*)d_in[5];
  const float* Wm2 = (const float*)d_in[6];
  const float* Wg  = (const float*)d_in[7];
  const float* W1  = (const float*)d_in[8];
  const float* b1  = (const float*)d_in[9];
  const float* W2  = (const float*)d_in[10];
  const float* b2  = (const float*)d_in[11];
  const float* W3  = (const float*)d_in[12];
  const float* b3  = (const float*)d_in[13];
  const float* We1 = (const float*)d_in[14];
  const float* be1 = (const float*)d_in[15];
  const float* We2 = (const float*)d_in[16];
  const float* be2 = (const float*)d_in[17];
  const float* We3 = (const float*)d_in[18];
  const float* be3 = (const float*)d_in[19];

  float* wsf = (float*)d_ws;
  float* AGGE   = wsf + OFF_AGGE;
  float* AGGO   = wsf + OFF_AGGO;
  float* NMASK  = wsf + OFF_NMASK;
  float* POOLF  = wsf + OFF_POOLF;
  float* POOLS  = wsf + OFF_POOLS;
  float* CNT    = wsf + OFF_CNT;
  unsigned* LCOUNT = (unsigned*)(wsf + OFF_LCOUNT);
  unsigned long long* SEGKEY = (unsigned long long*)(wsf + OFF_SEGKEY);
  unsigned* CNT2 = (unsigned*)(wsf + OFF_CNT2);
  float* Hbuf   = wsf + OFF_H;
  float* NRA    = wsf + OFF_NRA;
  float* BIAS1  = wsf + OFF_BIAS1;
  int*   ELIST  = (int*)(wsf + OFF_ELIST);
  int*   ELIST2 = (int*)(wsf + OFF_NRA);    // overlays NRA; consumed before k_node writes NRA
  unsigned short* PK = (unsigned short*)(wsf + OFF_AGGE);  // overlays AGGE, written after k_node
  float* out = (float*)d_out;

  hipMemsetAsync(wsf + OFF_POOLF, 0, (size_t)(ZERO_END - OFF_POOLF) * sizeof(float), stream);

  k_h     <<<NN/64,   256, 0, stream>>>(x, Wm1, Hbuf);
  k_bucket<<<EE/256,  256, 0, stream>>>(ei, y, LCOUNT, ELIST, CNT2, ELIST2);
  k_edges <<<BB*4,    256, 0, stream>>>(ei, Hbuf, CNT2, ELIST2, AGGE, AGGO, NMASK);
  k_node  <<<NN/8,    256, 0, stream>>>(Hbuf, AGGE, AGGO, Wm2, NMASK, NRA, POOLF, POOLS, CNT);
  k_pack  <<<60,      256, 0, stream>>>(W1, W2, W3, We1, We2, PK);
  k_graph <<<BB,      128, 0, stream>>>(POOLF, POOLS, CNT, Wg, y, We1, be1, BIAS1);
  k_mlp   <<<4*TPL,   256, 0, stream>>>(NRA, ei, PK, b1, b2, b3, be2, We3, be3,
                                        BIAS1, ELIST, LCOUNT, out, SEGKEY);
  k_final <<<1,        64, 0, stream>>>(SEGKEY, out);
}

// Round 6
// 722.499 us; speedup vs baseline: 1.7189x; 1.7189x over previous
//
#include <hip/hip_runtime.h>

#define NN 25600
#define EE 409600
#define BB 64
#define NGR 400
#define DD 128
#define HH 64
#define RR 32
#define EA 204800              // available (odd) edges
#define TPL (EA/32)            // tiles per label bucket = 6400

// workspace layout (float offsets)
#define OFF_AGGE   0
#define OFF_AGGO   1638400
#define OFF_NMASK  3276800
#define OFF_POOLF  3302400
#define OFF_POOLS  3304448
#define OFF_CNT    3306496
#define OFF_LCOUNT 3306560     // 4 uints
#define OFF_SEGKEY 3306568     // 64 u64 (8B-aligned)
#define OFF_CNT2   3306696     // 128 uints (graph x parity counters)
#define ZERO_END   3306824
#define OFF_H      3306824
#define OFF_NRA    4945224     // also overlays ELIST2 (consumed by k_edges before k_node writes)
#define OFF_BIAS1  5764424
#define OFF_ELIST  5772616     // 4*EA ints
// ELIST2: 128 buckets x 4096 ints at OFF_NRA (524288 <= 819200)
// weight packs overlay AGGE (dead after k_node); written by k_pack after k_node

typedef short bf16x8 __attribute__((ext_vector_type(8)));
typedef float floatx4 __attribute__((ext_vector_type(4)));
#define MFMA16 __builtin_amdgcn_mfma_f32_16x16x32_bf16

__device__ __forceinline__ float eluf(float v){ return v > 0.f ? v : expm1f(v); }

__device__ __forceinline__ void splitbf(float v, unsigned short& h, unsigned short& l){
  const unsigned u = __float_as_uint(v);
  h = (unsigned short)(u >> 16);
  const float hf = __uint_as_float(u & 0xFFFF0000u);
  l = (unsigned short)(__float_as_uint(v - hf) >> 16);
}
__device__ __forceinline__ float bf2f(unsigned short s){
  return __uint_as_float(((unsigned)s) << 16);
}

__device__ __forceinline__ unsigned long long packkey(float f, unsigned idx){
  unsigned u = __float_as_uint(f);
  u = (u & 0x80000000u) ? ~u : (u | 0x80000000u);
  return ((unsigned long long)u << 32) | (unsigned long long)(0xFFFFFFFFu - idx);
}

// ---------------- h = elu(x @ Wm1) ----------------
__global__ __launch_bounds__(256) void k_h(const float* __restrict__ x,
                                           const float* __restrict__ Wm1,
                                           float* __restrict__ h)
{
  __shared__ float xs[64][129];
  const int tid = threadIdx.x;
  const int n0 = blockIdx.x * 64;
  for (int idx = tid; idx < 64*128; idx += 256){
    int r = idx >> 7, c = idx & 127;
    xs[r][c] = x[(n0 + r)*DD + c];
  }
  __syncthreads();
  const int m = tid & 63, ng = tid >> 6;
  float4 acc[4];
  #pragma unroll
  for (int c = 0; c < 4; ++c) acc[c] = make_float4(0.f,0.f,0.f,0.f);
  for (int k = 0; k < 128; ++k){
    const float a = xs[m][k];
    const float* wr = Wm1 + k*64 + ng*16;
    #pragma unroll
    for (int c = 0; c < 4; ++c){
      const float4 w = *(const float4*)(wr + 4*c);
      acc[c].x += a*w.x; acc[c].y += a*w.y; acc[c].z += a*w.z; acc[c].w += a*w.w;
    }
  }
  float* hp = h + (n0 + m)*HH + ng*16;
  #pragma unroll
  for (int c = 0; c < 4; ++c){
    hp[4*c+0] = eluf(acc[c].x); hp[4*c+1] = eluf(acc[c].y);
    hp[4*c+2] = eluf(acc[c].z); hp[4*c+3] = eluf(acc[c].w);
  }
}

// ---------------- bucket ALL edges: block-local count -> reserve -> scatter ----------------
// 256 blocks x 1600 contiguous edges. Global atomics: <=132 per block (one per bucket).
__global__ __launch_bounds__(256) void k_bucket(const int* __restrict__ ei,
                                                const int* __restrict__ y,
                                                unsigned* __restrict__ lcount,
                                                int* __restrict__ elist,
                                                unsigned* __restrict__ cnt2,
                                                int* __restrict__ elist2)
{
  __shared__ unsigned cl[128], bl[128], ol[128];
  __shared__ unsigned lc[4], lb[4], lo[4];
  const int tid = threadIdx.x;
  const int e0 = blockIdx.x * (EE/256);       // 1600 edges per block
  if (tid < 128){ cl[tid] = 0; ol[tid] = 0; }
  if (tid < 4){ lc[tid] = 0; lo[tid] = 0; }
  __syncthreads();
  int bk[7]; int ne = 0;
  for (int e = e0 + tid; e < e0 + EE/256; e += 256){
    const int d = ei[EE + e];
    const int g = d / NGR;
    const int bkt = g*2 + (e & 1);
    bk[ne++] = bkt;
    atomicAdd(&cl[bkt], 1u);
    if (e & 1) atomicAdd(&lc[y[g]], 1u);
  }
  __syncthreads();
  if (tid < 128 && cl[tid]) bl[tid] = atomicAdd(&cnt2[tid], cl[tid]);
  if (tid < 4 && lc[tid])   lb[tid] = atomicAdd(&lcount[tid], lc[tid]);
  __syncthreads();
  ne = 0;
  for (int e = e0 + tid; e < e0 + EE/256; e += 256){
    const int bkt = bk[ne++];
    const unsigned r = atomicAdd(&ol[bkt], 1u);
    elist2[bkt*4096 + (int)(bl[bkt] + r)] = e;
    if (e & 1){
      const int l = y[bkt >> 1];              // bkt = g*2+1 -> g = bkt>>1
      const unsigned r2 = atomicAdd(&lo[l], 1u);
      elist[l*EA + (int)(lb[l] + r2)] = e >> 1;
    }
  }
}

// ---------------- edge aggregation: drain pre-bucketed edges into LDS ----------------
// block = g*4 + p*2 + ch; LDS 400x36 accumulator (stride 36 dwords => bank spread by d)
__global__ __launch_bounds__(256) void k_edges(const int* __restrict__ ei,
                                               const float* __restrict__ h,
                                               const unsigned* __restrict__ cnt2,
                                               const int* __restrict__ elist2,
                                               float* __restrict__ aggE,
                                               float* __restrict__ aggO,
                                               float* __restrict__ nmask)
{
  __shared__ float acc[400*36];
  __shared__ unsigned char mk[400];
  const int b = blockIdx.x;
  const int g = b >> 2, p = (b >> 1) & 1, ch = b & 1;
  const int tid = threadIdx.x;
  const int nlo = g * NGR;
  for (int i = tid; i < 400*36; i += 256) acc[i] = 0.f;
  if (tid < 400) mk[tid] = 0;
  __syncthreads();
  const int bkt = g*2 + p;
  const int n = (int)cnt2[bkt];
  const int j0 = tid >> 3, c8 = tid & 7;
  const bool domask = (p == 0) && (ch == 0) && (c8 == 0);
  for (int j = j0; j < n; j += 32){
    const int e = elist2[bkt*4096 + j];
    const int s = ei[e];
    const int d = ei[EE + e] - nlo;
    const float4 v = *(const float4*)(h + s*HH + ch*32 + c8*4);
    float* ap = &acc[d*36 + c8*4];
    atomicAdd(ap+0, v.x); atomicAdd(ap+1, v.y);
    atomicAdd(ap+2, v.z); atomicAdd(ap+3, v.w);
    if (domask){ mk[s - nlo] = 1; mk[d] = 1; }
  }
  __syncthreads();
  float* agg = p ? aggO : aggE;
  for (int idx = tid; idx < 400*32; idx += 256){
    const int d = idx >> 5, col = idx & 31;
    agg[(nlo + d)*HH + ch*32 + col] = acc[d*36 + col];
  }
  if (p == 0 && ch == 0){
    for (int idx = tid; idx < 400; idx += 256) nmask[nlo + idx] = (float)mk[idx];
  }
}

// ---------------- node reps + pooled sums (LDS-reduced pools) ----------------
__global__ __launch_bounds__(256) void k_node(const float* __restrict__ h,
                                              const float* __restrict__ aggE,
                                              const float* __restrict__ aggO,
                                              const float* __restrict__ Wm2,
                                              const float* __restrict__ nmask,
                                              float* __restrict__ nra,
                                              float* __restrict__ poolF,
                                              float* __restrict__ poolS,
                                              float* __restrict__ cntArr)
{
  __shared__ float hs[8][64], ae[8][64], ao[8][64];
  __shared__ float wm[64][32];
  __shared__ float rf[8][32], rs[8][32], rc[8];
  const int tid = threadIdx.x;
  const int n0 = blockIdx.x * 8;
  for (int idx = tid; idx < 512; idx += 256){
    int i = idx >> 6, k = idx & 63, n = n0 + i;
    hs[i][k] = h[n*HH + k];
    ae[i][k] = aggE[n*HH + k];
    ao[i][k] = aggO[n*HH + k];
  }
  for (int idx = tid; idx < 2048; idx += 256) wm[idx >> 5][idx & 31] = Wm2[idx];
  __syncthreads();
  const int i = tid >> 5, r = tid & 31;
  const int n = n0 + i;
  float aF = 0.f, aS = 0.f, aA = 0.f;
  #pragma unroll 4
  for (int k = 0; k < 64; ++k){
    const float th = hs[i][k], te = ae[i][k], to = ao[i][k], w = wm[k][r];
    aF += (th + te + to) * w;
    aS += (th + te) * w;
    aA += (th + to) * w;
  }
  aF = eluf(aF); aS = eluf(aS); aA = eluf(aA);
  nra[n*RR + r] = aA;
  const float msk = nmask[n];
  rf[i][r] = aF;
  rs[i][r] = (msk != 0.f) ? aS : 0.f;
  if (r == 0) rc[i] = (msk != 0.f) ? 1.f : 0.f;
  __syncthreads();
  const int g = n0 / NGR;
  if (tid < 32){
    float sf = 0.f, ss = 0.f;
    #pragma unroll
    for (int k = 0; k < 8; ++k){ sf += rf[k][tid]; ss += rs[k][tid]; }
    atomicAdd(&poolF[g*RR + tid], sf);
    atomicAdd(&poolS[g*RR + tid], ss);
  } else if (tid == 32){
    float sc = 0.f;
    #pragma unroll
    for (int k = 0; k < 8; ++k) sc += rc[k];
    atomicAdd(&cntArr[g], sc);
  }
}

// ---------------- pack all MLP weights into MFMA B-fragment hi/lo bf16 ----------------
__global__ __launch_bounds__(256) void k_pack(const float* __restrict__ W1,
                                              const float* __restrict__ W2,
                                              const float* __restrict__ W3,
                                              const float* __restrict__ We1,
                                              const float* __restrict__ We2,
                                              unsigned short* __restrict__ pk)
{
  const int t = blockIdx.x*4 + (threadIdx.x >> 6);   // 0..239
  const int L = threadIdx.x & 63;
  int tl, KT, N; const float* W;
  if (t < 32)      { tl = t;      KT = 2; N = 256; W = W1; }
  else if (t < 96) { tl = t-32;   KT = 8; N = 128; W = W2; }
  else if (t < 112){ tl = t-96;   KT = 4; N = 64;  W = W3; }
  else if (t < 176){ int u = t-112; int lb = u >> 4; tl = u & 15; KT = 2; N = 128; W = We1 + lb*16384; }
  else             { int u = t-176; int lb = u >> 4; tl = u & 15; KT = 4; N = 64;  W = We2 + lb*8192; }
  const int nt = tl / KT, kt = tl % KT;
  const int krow = kt*32 + (L >> 4)*8;
  const int col  = nt*16 + (L & 15);
  unsigned short* dh = pk + (unsigned)t*1024 + L*8;
  unsigned short* dl = dh + 512;
  #pragma unroll
  for (int j = 0; j < 8; ++j){
    const float v = W[(krow + j)*N + col];
    unsigned short h, l2;
    splitbf(v, h, l2);
    dh[j] = h; dl[j] = l2;
  }
}

// ---------------- per-graph diff and explainer bias ----------------
__global__ __launch_bounds__(128) void k_graph(const float* __restrict__ poolF,
                                               const float* __restrict__ poolS,
                                               const float* __restrict__ cnt,
                                               const float* __restrict__ Wg,
                                               const int* __restrict__ y,
                                               const float* __restrict__ We1,
                                               const float* __restrict__ be1,
                                               float* __restrict__ bias1)
{
  __shared__ float pd[32];
  __shared__ float dg[64];
  const int g = blockIdx.x, tid = threadIdx.x;
  if (tid < 32){
    const float c = cnt[g];
    const float pf = poolF[g*RR + tid] * (1.0f/400.0f);
    const float ps = poolS[g*RR + tid] / fmaxf(c, 1.0f);
    pd[tid] = pf - ps;
  }
  __syncthreads();
  if (tid < 64){
    float a = 0.f;
    #pragma unroll
    for (int r = 0; r < 32; ++r) a += pd[r] * Wg[r*64 + tid];
    dg[tid] = a;
  }
  __syncthreads();
  const int l = y[g];
  float acc = be1[l*128 + tid];
  #pragma unroll 8
  for (int j = 0; j < 64; ++j) acc += dg[j] * We1[l*16384 + (64 + j)*128 + tid];
  bias1[g*128 + tid] = acc;
}

// ---------------- MFMA split-bf16 layer: 4 waves split N, double-buffered B prefetch ----------------
template<int K, int N, bool DOELU, int SIN, int SOUT, bool ROWBIAS>
__device__ __forceinline__ void layerM(const unsigned short (*__restrict__ Ih)[SIN],
                                       const unsigned short (*__restrict__ Il)[SIN],
                                       unsigned short (*__restrict__ Oh)[SOUT],
                                       unsigned short (*__restrict__ Ol)[SOUT],
                                       const unsigned short* __restrict__ pk,
                                       const float* __restrict__ bias,
                                       const int* __restrict__ gA,
                                       int wv, int lane)
{
  constexpr int KT = K/32, NTW = N/64;   // k-tiles; n-tiles per wave
  const int c = lane & 15, q = lane >> 4;
  floatx4 acc[2][NTW];
  #pragma unroll
  for (int ms = 0; ms < 2; ++ms){
    #pragma unroll
    for (int nt = 0; nt < NTW; ++nt){
      const int col = (wv*NTW + nt)*16 + c;
      if (ROWBIAS){
        #pragma unroll
        for (int r = 0; r < 4; ++r)
          acc[ms][nt][r] = bias[gA[ms*16 + q*4 + r]*128 + col];
      } else {
        const float bv = bias[col];
        acc[ms][nt][0]=bv; acc[ms][nt][1]=bv; acc[ms][nt][2]=bv; acc[ms][nt][3]=bv;
      }
    }
  }
  bf16x8 BH[2][NTW], BL[2][NTW];
  #pragma unroll
  for (int nt = 0; nt < NTW; ++nt){
    const unsigned short* bp = pk + (unsigned)((wv*NTW + nt)*KT*1024) + lane*8;
    BH[0][nt] = *(const bf16x8*)bp;
    BL[0][nt] = *(const bf16x8*)(bp + 512);
  }
  #pragma unroll
  for (int kt = 0; kt < KT; ++kt){
    const int cur = kt & 1, nxt = cur ^ 1;
    if (kt + 1 < KT){
      #pragma unroll
      for (int nt = 0; nt < NTW; ++nt){
        const unsigned short* bp = pk + (unsigned)(((wv*NTW + nt)*KT + kt + 1)*1024) + lane*8;
        BH[nxt][nt] = *(const bf16x8*)bp;
        BL[nxt][nt] = *(const bf16x8*)(bp + 512);
      }
    }
    const bf16x8 ah0 = *(const bf16x8*)&Ih[c     ][kt*32 + q*8];
    const bf16x8 al0 = *(const bf16x8*)&Il[c     ][kt*32 + q*8];
    const bf16x8 ah1 = *(const bf16x8*)&Ih[16 + c][kt*32 + q*8];
    const bf16x8 al1 = *(const bf16x8*)&Il[16 + c][kt*32 + q*8];
    #pragma unroll
    for (int nt = 0; nt < NTW; ++nt){
      acc[0][nt] = MFMA16(ah0, BH[cur][nt], acc[0][nt], 0, 0, 0);
      acc[1][nt] = MFMA16(ah1, BH[cur][nt], acc[1][nt], 0, 0, 0);
      acc[0][nt] = MFMA16(al0, BH[cur][nt], acc[0][nt], 0, 0, 0);
      acc[1][nt] = MFMA16(al1, BH[cur][nt], acc[1][nt], 0, 0, 0);
      acc[0][nt] = MFMA16(ah0, BL[cur][nt], acc[0][nt], 0, 0, 0);
      acc[1][nt] = MFMA16(ah1, BL[cur][nt], acc[1][nt], 0, 0, 0);
    }
  }
  #pragma unroll
  for (int ms = 0; ms < 2; ++ms){
    #pragma unroll
    for (int nt = 0; nt < NTW; ++nt){
      const int col = (wv*NTW + nt)*16 + c;
      #pragma unroll
      for (int r = 0; r < 4; ++r){
        float v = acc[ms][nt][r];
        if (DOELU) v = eluf(v);
        unsigned short h, l2;
        splitbf(v, h, l2);
        const int row = ms*16 + q*4 + r;
        Oh[row][col] = h; Ol[row][col] = l2;
      }
    }
  }
}

// ---------------- fused per-edge MLP (MFMA) ----------------
__global__ __launch_bounds__(256, 3) void k_mlp(const float* __restrict__ nra,
                                             const int* __restrict__ ei,
                                             const unsigned short* __restrict__ pk,
                                             const float* __restrict__ b1,
                                             const float* __restrict__ b2,
                                             const float* __restrict__ b3,
                                             const float* __restrict__ be2,
                                             const float* __restrict__ We3,
                                             const float* __restrict__ be3,
                                             const float* __restrict__ bias1,
                                             const int* __restrict__ elist,
                                             const unsigned* __restrict__ lcount,
                                             float* __restrict__ probs,
                                             unsigned long long* __restrict__ segkey)
{
  __shared__ unsigned short Xh[32][264], Xl[32][264];
  __shared__ unsigned short Yh[32][136], Yl[32][136];
  __shared__ int iA[32], sA[32], dA[32], gA[32];
  const int l = blockIdx.x / TPL;
  const int t = blockIdx.x % TPL;
  const unsigned cnt = lcount[l];
  const int base = t * 32;
  if ((unsigned)base >= cnt) return;
  const int valid = min(32, (int)(cnt - (unsigned)base));
  const int tid = threadIdx.x;
  const int wv = tid >> 6, lane = tid & 63;
  if (tid < 32){
    const int mm = (tid < valid) ? tid : 0;
    const int i = elist[l*EA + base + mm];
    const int e = 2*i + 1;
    const int s = ei[e], d = ei[EE + e];
    iA[tid] = i; sA[tid] = s; dA[tid] = d; gA[tid] = s / NGR;
  }
  __syncthreads();
  { // gather in0 = [nr_ava[src] | nr_ava[dst]] split into Yh/Yl cols 0..63
    const int m = tid >> 3, t8 = tid & 7;
    const int node = (t8 < 4) ? sA[m] : dA[m];
    const int off = (t8 & 3) * 8;
    const float* np_ = nra + node*RR + off;
    const int cb = ((t8 < 4) ? 0 : 32) + off;
    #pragma unroll
    for (int jj = 0; jj < 8; ++jj){
      unsigned short h, l2;
      splitbf(np_[jj], h, l2);
      Yh[m][cb + jj] = h; Yl[m][cb + jj] = l2;
    }
  }
  __syncthreads();
  layerM< 64,256,true ,136,264,false>(Yh,Yl,Xh,Xl, pk,                     b1,         gA, wv, lane);
  __syncthreads();
  layerM<256,128,true ,264,136,false>(Xh,Xl,Yh,Yl, pk + 32*1024,           b2,         gA, wv, lane);
  __syncthreads();
  layerM<128, 64,false,136,264,false>(Yh,Yl,Xh,Xl, pk + 96*1024,           b3,         gA, wv, lane);
  __syncthreads();
  layerM< 64,128,true ,264,136,true >(Xh,Xl,Yh,Yl, pk + (112 + l*16)*1024, bias1,      gA, wv, lane);
  __syncthreads();
  layerM<128, 64,true ,136,264,false>(Yh,Yl,Xh,Xl, pk + (176 + l*16)*1024, be2 + l*64, gA, wv, lane);
  __syncthreads();
  if (tid < 128){ // score = X5 . We3[l] + be3[l]; 4 threads per edge
    const int m = tid >> 2, part = tid & 3;
    const float* w3p = We3 + l*64 + part*16;
    const unsigned short* xh = &Xh[m][part*16];
    const unsigned short* xl = &Xl[m][part*16];
    float s = 0.f;
    #pragma unroll
    for (int kk = 0; kk < 16; ++kk)
      s += (bf2f(xh[kk]) + bf2f(xl[kk])) * w3p[kk];
    s += __shfl_down(s, 2);
    s += __shfl_down(s, 1);
    if (part == 0 && m < valid){
      s += be3[l];
      const int i = iA[m];
      probs[i] = s;
      atomicMax(&segkey[gA[m]], packkey(s, (unsigned)i));
    }
  }
}

// ---------------- finalize outputs ----------------
__global__ void k_final(const unsigned long long* __restrict__ segkey, float* __restrict__ out)
{
  const int g = threadIdx.x;
  if (g < BB){
    const unsigned long long key = segkey[g];
    const unsigned u = (unsigned)(key >> 32);
    const float mx = (u & 0x80000000u) ? __uint_as_float(u & 0x7FFFFFFFu)
                                       : __uint_as_float(~u);
    const unsigned idx = 0xFFFFFFFFu - (unsigned)(key & 0xFFFFFFFFull);
    out[EA + g]        = mx;
    out[EA + BB + g]   = (float)idx;
    out[EA + 2*BB + g] = (float)g;
  }
}

extern "C" void kernel_launch(void* const* d_in, const int* in_sizes, int n_in,
                              void* d_out, int out_size, void* d_ws, size_t ws_size,
                              hipStream_t stream)
{
  (void)in_sizes; (void)n_in; (void)out_size; (void)ws_size;
  const float* x   = (const float*)d_in[0];
  const int*   ei  = (const int*)  d_in[1];
  const int*   y   = (const int*)  d_in[3];
  const float* Wm1 = (const float*)d_in[5];
  const float* Wm2 = (const float*)d_in[6];
  const float* Wg  = (const float*)d_in[7];
  const float* W1  = (const float*)d_in[8];
  const float* b1  = (const float*)d_in[9];
  const float* W2  = (const float*)d_in[10];
  const float* b2  = (const float*)d_in[11];
  const float* W3  = (const float*)d_in[12];
  const float* b3  = (const float*)d_in[13];
  const float* We1 = (const float*)d_in[14];
  const float* be1 = (const float*)d_in[15];
  const float* We2 = (const float*)d_in[16];
  const float* be2 = (const float*)d_in[17];
  const float* We3 = (const float*)d_in[18];
  const float* be3 = (const float*)d_in[19];

  float* wsf = (float*)d_ws;
  float* AGGE   = wsf + OFF_AGGE;
  float* AGGO   = wsf + OFF_AGGO;
  float* NMASK  = wsf + OFF_NMASK;
  float* POOLF  = wsf + OFF_POOLF;
  float* POOLS  = wsf + OFF_POOLS;
  float* CNT    = wsf + OFF_CNT;
  unsigned* LCOUNT = (unsigned*)(wsf + OFF_LCOUNT);
  unsigned long long* SEGKEY = (unsigned long long*)(wsf + OFF_SEGKEY);
  unsigned* CNT2 = (unsigned*)(wsf + OFF_CNT2);
  float* Hbuf   = wsf + OFF_H;
  float* NRA    = wsf + OFF_NRA;
  float* BIAS1  = wsf + OFF_BIAS1;
  int*   ELIST  = (int*)(wsf + OFF_ELIST);
  int*   ELIST2 = (int*)(wsf + OFF_NRA);    // overlays NRA; consumed before k_node writes NRA
  unsigned short* PK = (unsigned short*)(wsf + OFF_AGGE);  // overlays AGGE, written after k_node
  float* out = (float*)d_out;

  hipMemsetAsync(wsf + OFF_POOLF, 0, (size_t)(ZERO_END - OFF_POOLF) * sizeof(float), stream);

  k_h     <<<NN/64,   256, 0, stream>>>(x, Wm1, Hbuf);
  k_bucket<<<256,     256, 0, stream>>>(ei, y, LCOUNT, ELIST, CNT2, ELIST2);
  k_edges <<<BB*4,    256, 0, stream>>>(ei, Hbuf, CNT2, ELIST2, AGGE, AGGO, NMASK);
  k_node  <<<NN/8,    256, 0, stream>>>(Hbuf, AGGE, AGGO, Wm2, NMASK, NRA, POOLF, POOLS, CNT);
  k_pack  <<<60,      256, 0, stream>>>(W1, W2, W3, We1, We2, PK);
  k_graph <<<BB,      128, 0, stream>>>(POOLF, POOLS, CNT, Wg, y, We1, be1, BIAS1);
  k_mlp   <<<4*TPL,   256, 0, stream>>>(NRA, ei, PK, b1, b2, b3, be2, We3, be3,
                                        BIAS1, ELIST, LCOUNT, out, SEGKEY);
  k_final <<<1,        64, 0, stream>>>(SEGKEY, out);
}